// Round 1
// baseline (1055.602 us; speedup 1.0000x reference)
//
#include <hip/hip_runtime.h>
#include <cmath>
#include <complex>

#define NT 256

struct CgPack { float v[363]; };

// ======================= host-side Wigner 3j (e3nn convention) =======================
static double factd(int n) { double r = 1.0; for (int i = 2; i <= n; ++i) r *= i; return r; }

static void su2_cg(int j1, int j2, int j3, double C[5][5][5]) {
  for (int a = 0; a < 5; ++a) for (int b = 0; b < 5; ++b) for (int c = 0; c < 5; ++c) C[a][b][c] = 0.0;
  for (int m1 = -j1; m1 <= j1; ++m1)
    for (int m2 = -j2; m2 <= j2; ++m2) {
      int m3 = m1 + m2;
      if (m3 < -j3 || m3 > j3) continue;
      int vmin = -j1 + j2 + m3; if (-j1 + m1 > vmin) vmin = -j1 + m1; if (vmin < 0) vmin = 0;
      int vmax = j2 + j3 + m1; if (j3 - j1 + j2 < vmax) vmax = j3 - j1 + j2; if (j3 + m3 < vmax) vmax = j3 + m3;
      double c = std::sqrt((2.0 * j3 + 1.0) *
            factd(j3 + j1 - j2) * factd(j3 - j1 + j2) * factd(j1 + j2 - j3) * factd(j3 + m3) * factd(j3 - m3) /
            (factd(j1 + j2 + j3 + 1) * factd(j1 - m1) * factd(j1 + m1) * factd(j2 - m2) * factd(j2 + m2)));
      double S = 0.0;
      for (int v = vmin; v <= vmax; ++v) {
        double t = factd(j2 + j3 + m1 - v) * factd(j1 - m1 + v) /
                   (factd(v) * factd(j3 - j1 + j2 - v) * factd(j3 + m3 - v) * factd(v + j1 - j2 - m3));
        S += (((v + j2 + m2) & 1) ? -t : t);
      }
      C[j1 + m1][j2 + m2][j3 + m3] = c * S;
    }
}

typedef std::complex<double> cd;
static void qmat(int l, cd q[5][5]) {
  for (int a = 0; a < 5; ++a) for (int b = 0; b < 5; ++b) q[a][b] = cd(0.0, 0.0);
  const double is2 = 1.0 / std::sqrt(2.0);
  for (int m = -l; m < 0; ++m) { q[l + m][l - m] = cd(is2, 0.0); q[l + m][l + m] = cd(0.0, -is2); }
  q[l][l] = cd(1.0, 0.0);
  for (int m = 1; m <= l; ++m) {
    double sg = (m & 1) ? -1.0 : 1.0;
    q[l + m][l + m] = cd(sg * is2, 0.0);
    q[l + m][l - m] = cd(0.0, sg * is2);
  }
  cd ph(1.0, 0.0); const cd mi(0.0, -1.0);
  for (int t = 0; t < l; ++t) ph *= mi;   // (-i)^l
  for (int a = 0; a <= 2 * l; ++a) for (int b = 0; b <= 2 * l; ++b) q[a][b] *= ph;
}

static void w3j_fill(int l1, int l2, int l3, float* outp) {
  double C[5][5][5]; su2_cg(l1, l2, l3, C);
  cd q1[5][5], q2[5][5], q3[5][5];
  qmat(l1, q1); qmat(l2, q2); qmat(l3, q3);
  const int d1 = 2 * l1 + 1, d2 = 2 * l2 + 1, d3 = 2 * l3 + 1;
  double R[5][5][5]; double nrm = 0.0;
  for (int j = 0; j < d1; ++j)
    for (int L = 0; L < d2; ++L)
      for (int m = 0; m < d3; ++m) {
        cd s(0.0, 0.0);
        for (int i = 0; i < d1; ++i)
          for (int k = 0; k < d2; ++k)
            for (int n = 0; n < d3; ++n)
              s += q1[i][j] * q2[k][L] * std::conj(q3[n][m]) * C[i][k][n];
        R[j][L][m] = s.real();
        nrm += s.real() * s.real();
      }
  const double inv = 1.0 / std::sqrt(nrm);
  for (int j = 0; j < d1; ++j)
    for (int L = 0; L < d2; ++L)
      for (int m = 0; m < d3; ++m)
        outp[(j * d2 + L) * d3 + m] = (float)(R[j][L][m] * inv);
}

static void build_cg(CgPack* cg) {
  const int L1[11] = {0,0,0,1,1,1,1,2,2,2,2};
  const int L2[11] = {0,1,2,0,1,1,2,0,1,2,2};
  const int L3[11] = {0,1,2,1,0,2,1,2,1,0,2};
  const int CGO[11]= {0,1,10,35,44,53,98,143,168,213,238};
  for (int p = 0; p < 11; ++p) w3j_fill(L1[p], L2[p], L3[p], &cg->v[CGO[p]]);
}

// ======================= device-side path constants =======================
constexpr int cP_l1[11] = {0,0,0,1,1,1,1,2,2,2,2};
constexpr int cP_l2[11] = {0,1,2,0,1,1,2,0,1,2,2};
constexpr int cP_l3[11] = {0,1,2,1,0,2,1,2,1,0,2};
constexpr int cP_wo[11] = {0,1024,1536,1792,2048,2560,2688,2944,3008,3136,3392};
constexpr int cP_cgo[11]= {0,1,10,35,44,53,98,143,168,213,238};
constexpr int mul_of_l(int l)    { return l == 0 ? 32 : (l == 1 ? 16 : 8); }
constexpr int off_in_of_l(int l) { return l == 0 ? 0  : (l == 1 ? 32 : 80); }
constexpr int off_sh_of_l(int l) { return l == 0 ? 0  : (l == 1 ? 1  : 4); }
constexpr int log2i(int x)       { return x == 32 ? 5 : (x == 16 ? 4 : 3); }

__device__ __forceinline__ float silu_f(float x) { return x / (1.0f + __expf(-x)); }

// one tensor-product path: build tmp, tiled weight-GEMM chunks, contract into msg
template<int P>
__device__ void do_path(const CgPack& cg,
                        const float* __restrict__ w3, const float* __restrict__ b3,
                        float (&x1s)[64][121], float (&x2s)[64][13], float* tmpT,
                        float (&Cs)[64][132], float (&Hs)[64][64], float (&msg)[64][120])
{
  constexpr int l1 = cP_l1[P], l2 = cP_l2[P], l3 = cP_l3[P];
  constexpr int m1 = mul_of_l(l1), m3 = mul_of_l(l3);
  constexpr int d1 = 2*l1+1, d2 = 2*l2+1, d3 = 2*l3+1;
  constexpr int off1 = off_in_of_l(l1);
  constexpr int off2 = off_sh_of_l(l2);
  constexpr int off3 = off_in_of_l(l3);
  constexpr int wo = cP_wo[P], cgo = cP_cgo[P];
  constexpr float coeff = (l3==0) ? 0.13363062095621219f
                         : (l3==1) ? 0.20412414523193154f
                                   : 0.27950849718747373f;
  constexpr int cols = m1 * m3;
  constexpr int CW   = (cols < 128) ? cols : 128;   // 64 or 128
  constexpr int NCH  = cols / CW;
  constexpr int JT   = CW / 16;                      // cols per thread in GEMM: 8 or 4
  constexpr int g    = m3 / 4;                       // edges per TP task: 8/4/2
  constexpr int L2M3 = log2i(m3);
  constexpr int NU   = CW / m3;                      // u's per chunk

  const int tid = threadIdx.x;

  // ---- tmp[e,u,k] = sum_{i,j} x1[e,u,i]*x2[e,j]*cg[i,j,k], stored as tmpT[(u*d3+k)*64 + e]
  for (int idx = tid; idx < 64 * m1; idx += NT) {
    const int e = idx & 63, u = idx >> 6;
    float t[d3];
    #pragma unroll
    for (int k = 0; k < d3; ++k) t[k] = 0.0f;
    #pragma unroll
    for (int i = 0; i < d1; ++i) {
      const float a = x1s[e][off1 + u*d1 + i];
      #pragma unroll
      for (int j = 0; j < d2; ++j) {
        const float ab = a * x2s[e][off2 + j];
        #pragma unroll
        for (int k = 0; k < d3; ++k) t[k] += ab * cg.v[cgo + (i*d2 + j)*d3 + k];
      }
    }
    #pragma unroll
    for (int k = 0; k < d3; ++k) tmpT[(u*d3 + k)*64 + e] = t[k];
  }
  __syncthreads();

  for (int ch = 0; ch < NCH; ++ch) {
    const int col0 = ch * CW;
    // ---- GEMM: weights[e][col0+cl] = sum_c h2[e][c] * w3[c][wo+col0+cl] -> Cs[e][cl]
    {
      const int te = tid >> 4, tj = tid & 15;
      const int e_t = te * 4, j0 = tj * JT;
      const int jg = wo + col0 + j0;
      float acc[4][JT];
      #pragma unroll
      for (int i = 0; i < 4; ++i)
        #pragma unroll
        for (int jj = 0; jj < JT; ++jj) acc[i][jj] = 0.0f;

      #pragma unroll 8
      for (int c = 0; c < 64; ++c) {
        const float4 he = *(const float4*)(&Hs[c][e_t]);
        const float* wr = w3 + (size_t)c * 3456 + jg;
        float wjv[JT];
        { const float4 wa = *(const float4*)wr;
          wjv[0]=wa.x; wjv[1]=wa.y; wjv[2]=wa.z; wjv[3]=wa.w; }
        if constexpr (JT == 8) {
          const float4 wb = *(const float4*)(wr + 4);
          wjv[4]=wb.x; wjv[5]=wb.y; wjv[6]=wb.z; wjv[7]=wb.w;
        }
        #pragma unroll
        for (int jj = 0; jj < JT; ++jj) {
          const float wv = wjv[jj];
          acc[0][jj] += he.x * wv;
          acc[1][jj] += he.y * wv;
          acc[2][jj] += he.z * wv;
          acc[3][jj] += he.w * wv;
        }
      }
      #pragma unroll
      for (int i = 0; i < 4; ++i) {
        *(float4*)(&Cs[e_t + i][j0]) = make_float4(acc[i][0], acc[i][1], acc[i][2], acc[i][3]);
        if constexpr (JT == 8)
          *(float4*)(&Cs[e_t + i][j0 + 4]) = make_float4(acc[i][4], acc[i][5], acc[i][6], acc[i][7]);
      }
    }
    __syncthreads();
    // ---- TP contract: msg[e][off3+v*d3+k] += coeff * sum_u (Cs[e][u_l*m3+v]+b3) * tmp[e,u,k]
    {
      const int v  = tid & (m3 - 1);
      const int eg = tid >> L2M3;
      const int eb = eg * g;
      const int u0 = col0 >> L2M3;
      float av[g * d3];
      #pragma unroll
      for (int q = 0; q < g * d3; ++q) av[q] = 0.0f;
      #pragma unroll
      for (int ul = 0; ul < NU; ++ul) {
        const int u = u0 + ul;
        const float b3v = b3[wo + u*m3 + v];
        #pragma unroll
        for (int ei = 0; ei < g; ++ei) {
          const float w = Cs[eb + ei][ul*m3 + v] + b3v;
          #pragma unroll
          for (int k = 0; k < d3; ++k)
            av[ei*d3 + k] += w * tmpT[(u*d3 + k)*64 + eb + ei];
        }
      }
      #pragma unroll
      for (int ei = 0; ei < g; ++ei)
        #pragma unroll
        for (int k = 0; k < d3; ++k)
          msg[eb + ei][off3 + v*d3 + k] += coeff * av[ei*d3 + k];
    }
    __syncthreads();
  }
}

// ======================= fused MLP + TP + scatter kernel =======================
__global__ __launch_bounds__(NT, 1)
void tp_fused(const float* __restrict__ nf, const int* __restrict__ eidx,
              const float* __restrict__ sh, const float* __restrict__ rad,
              const float* __restrict__ w1, const float* __restrict__ b1,
              const float* __restrict__ w2, const float* __restrict__ b2,
              const float* __restrict__ w3, const float* __restrict__ b3,
              float* __restrict__ agg, const int E, const CgPack cg)
{
  __shared__ float Hs[64][64];        // h2 transposed: Hs[c][e]
  __shared__ float x1s[64][121];      // gathered node features (pad 121)
  __shared__ float x2s[64][13];       // edge SH (pad 13)
  __shared__ float msg[64][120];      // per-edge message accumulator
  __shared__ float tmpT[160 * 64];    // tmp transposed: [(u*d3+k)][e]
  __shared__ float Cs[64][132];       // weight chunk [e][col] (pad 132); aliased as h1T in phase A

  const int tid = threadIdx.x;
  const int e0  = blockIdx.x * 64;
  float* h1T = &Cs[0][0];             // 64*64 h1 transposed: h1T[c*64+e]

  // ---- phase A1: h1 = silu(rad @ w1 + b1), plus stage x1/x2/zero msg
  for (int idx = tid; idx < 64 * 64; idx += NT) {
    const int c = idx >> 6, e = idx & 63;
    const float4* r4 = (const float4*)(rad + (size_t)(e0 + e) * 8);
    const float4 ra = r4[0], rb = r4[1];
    float a = b1[c];
    a += ra.x * w1[0*64+c] + ra.y * w1[1*64+c] + ra.z * w1[2*64+c] + ra.w * w1[3*64+c];
    a += rb.x * w1[4*64+c] + rb.y * w1[5*64+c] + rb.z * w1[6*64+c] + rb.w * w1[7*64+c];
    h1T[c * 64 + e] = silu_f(a);
  }
  for (int idx = tid; idx < 64 * 120; idx += NT) {
    const int e = idx / 120, d = idx - e * 120;
    const int s = eidx[e0 + e];
    x1s[e][d] = nf[(size_t)s * 120 + d];
    msg[e][d] = 0.0f;
  }
  for (int idx = tid; idx < 64 * 9; idx += NT) {
    const int e = idx / 9, j = idx - e * 9;
    x2s[e][j] = sh[(size_t)(e0 + e) * 9 + j];
  }
  __syncthreads();

  // ---- phase A2: h2 = silu(h1 @ w2 + b2) -> Hs[c][e]
  for (int idx = tid; idx < 64 * 16; idx += NT) {
    const int c = idx >> 4, eq = (idx & 15) * 4;
    float a0 = b2[c], a1 = b2[c], a2 = b2[c], a3 = b2[c];
    #pragma unroll 8
    for (int i = 0; i < 64; ++i) {
      const float wv = w2[i * 64 + c];
      const float4 h4 = *(const float4*)(&h1T[i * 64 + eq]);
      a0 += h4.x * wv; a1 += h4.y * wv; a2 += h4.z * wv; a3 += h4.w * wv;
    }
    *(float4*)(&Hs[c][eq]) = make_float4(silu_f(a0), silu_f(a1), silu_f(a2), silu_f(a3));
  }
  __syncthreads();

  // ---- all 11 tensor-product paths
  do_path<0>(cg, w3, b3, x1s, x2s, tmpT, Cs, Hs, msg);
  do_path<1>(cg, w3, b3, x1s, x2s, tmpT, Cs, Hs, msg);
  do_path<2>(cg, w3, b3, x1s, x2s, tmpT, Cs, Hs, msg);
  do_path<3>(cg, w3, b3, x1s, x2s, tmpT, Cs, Hs, msg);
  do_path<4>(cg, w3, b3, x1s, x2s, tmpT, Cs, Hs, msg);
  do_path<5>(cg, w3, b3, x1s, x2s, tmpT, Cs, Hs, msg);
  do_path<6>(cg, w3, b3, x1s, x2s, tmpT, Cs, Hs, msg);
  do_path<7>(cg, w3, b3, x1s, x2s, tmpT, Cs, Hs, msg);
  do_path<8>(cg, w3, b3, x1s, x2s, tmpT, Cs, Hs, msg);
  do_path<9>(cg, w3, b3, x1s, x2s, tmpT, Cs, Hs, msg);
  do_path<10>(cg, w3, b3, x1s, x2s, tmpT, Cs, Hs, msg);

  // ---- scatter: agg[dst] += msg  (last do_path ended with a barrier)
  for (int idx = tid; idx < 64 * 120; idx += NT) {
    const int e = idx / 120, d = idx - e * 120;
    const int dn = eidx[E + e0 + e];
    atomicAdd(&agg[(size_t)dn * 120 + d], msg[e][d]);
  }
}

// ======================= self-interaction + residual =======================
__global__ __launch_bounds__(128)
void si_kernel(const float* __restrict__ agg, const float* __restrict__ nf,
               const float* __restrict__ w0, const float* __restrict__ wl1,
               const float* __restrict__ wl2, float* __restrict__ out)
{
  __shared__ float a[120];
  const int n = blockIdx.x, tid = threadIdx.x;
  if (tid < 120) a[tid] = agg[(size_t)n * 120 + tid];
  __syncthreads();
  if (tid >= 120) return;
  float s = 0.0f;
  if (tid < 32) {
    const int v = tid;
    #pragma unroll
    for (int u = 0; u < 32; ++u) s += a[u] * w0[u * 32 + v];
    s *= 0.17677669529663687f;    // 1/sqrt(32)
  } else if (tid < 80) {
    const int r = tid - 32, v = r / 3, k = r - 3 * v;
    #pragma unroll
    for (int u = 0; u < 16; ++u) s += a[32 + u * 3 + k] * wl1[u * 16 + v];
    s *= 0.25f;                   // 1/sqrt(16)
  } else {
    const int r = tid - 80, v = r / 5, k = r - 5 * v;
    #pragma unroll
    for (int u = 0; u < 8; ++u) s += a[80 + u * 5 + k] * wl2[u * 8 + v];
    s *= 0.35355339059327373f;    // 1/sqrt(8)
  }
  out[(size_t)n * 120 + tid] = s + nf[(size_t)n * 120 + tid];
}

// ======================= launch =======================
extern "C" void kernel_launch(void* const* d_in, const int* in_sizes, int n_in,
                              void* d_out, int out_size, void* d_ws, size_t ws_size,
                              hipStream_t stream) {
  const float* nf  = (const float*)d_in[0];
  const int*   ei  = (const int*)  d_in[1];
  const float* sh  = (const float*)d_in[2];
  const float* rad = (const float*)d_in[3];
  const float* w1  = (const float*)d_in[4];
  const float* b1  = (const float*)d_in[5];
  const float* w2  = (const float*)d_in[6];
  const float* b2  = (const float*)d_in[7];
  const float* w3  = (const float*)d_in[8];
  const float* b3  = (const float*)d_in[9];
  const float* si0 = (const float*)d_in[10];
  const float* si1 = (const float*)d_in[11];
  const float* si2 = (const float*)d_in[12];
  float* out = (float*)d_out;

  const int N = in_sizes[0] / 120;
  const int E = in_sizes[2] / 9;

  float* agg = (float*)d_ws;
  hipMemsetAsync(agg, 0, (size_t)N * 120 * sizeof(float), stream);

  CgPack cg;
  build_cg(&cg);

  tp_fused<<<E / 64, NT, 0, stream>>>(nf, ei, sh, rad, w1, b1, w2, b2, w3, b3, agg, E, cg);
  si_kernel<<<N, 128, 0, stream>>>(agg, nf, si0, si1, si2, out);
}

// Round 2
// 585.186 us; speedup vs baseline: 1.8039x; 1.8039x over previous
//
#include <hip/hip_runtime.h>
#include <cmath>
#include <complex>

#define NT 512

struct CgPack { float v[363]; };

// ======================= host-side Wigner 3j (e3nn convention) =======================
static double factd(int n) { double r = 1.0; for (int i = 2; i <= n; ++i) r *= i; return r; }

static void su2_cg(int j1, int j2, int j3, double C[5][5][5]) {
  for (int a = 0; a < 5; ++a) for (int b = 0; b < 5; ++b) for (int c = 0; c < 5; ++c) C[a][b][c] = 0.0;
  for (int m1 = -j1; m1 <= j1; ++m1)
    for (int m2 = -j2; m2 <= j2; ++m2) {
      int m3 = m1 + m2;
      if (m3 < -j3 || m3 > j3) continue;
      int vmin = -j1 + j2 + m3; if (-j1 + m1 > vmin) vmin = -j1 + m1; if (vmin < 0) vmin = 0;
      int vmax = j2 + j3 + m1; if (j3 - j1 + j2 < vmax) vmax = j3 - j1 + j2; if (j3 + m3 < vmax) vmax = j3 + m3;
      double c = std::sqrt((2.0 * j3 + 1.0) *
            factd(j3 + j1 - j2) * factd(j3 - j1 + j2) * factd(j1 + j2 - j3) * factd(j3 + m3) * factd(j3 - m3) /
            (factd(j1 + j2 + j3 + 1) * factd(j1 - m1) * factd(j1 + m1) * factd(j2 - m2) * factd(j2 + m2)));
      double S = 0.0;
      for (int v = vmin; v <= vmax; ++v) {
        double t = factd(j2 + j3 + m1 - v) * factd(j1 - m1 + v) /
                   (factd(v) * factd(j3 - j1 + j2 - v) * factd(j3 + m3 - v) * factd(v + j1 - j2 - m3));
        S += (((v + j2 + m2) & 1) ? -t : t);
      }
      C[j1 + m1][j2 + m2][j3 + m3] = c * S;
    }
}

typedef std::complex<double> cd;
static void qmat(int l, cd q[5][5]) {
  for (int a = 0; a < 5; ++a) for (int b = 0; b < 5; ++b) q[a][b] = cd(0.0, 0.0);
  const double is2 = 1.0 / std::sqrt(2.0);
  for (int m = -l; m < 0; ++m) { q[l + m][l - m] = cd(is2, 0.0); q[l + m][l + m] = cd(0.0, -is2); }
  q[l][l] = cd(1.0, 0.0);
  for (int m = 1; m <= l; ++m) {
    double sg = (m & 1) ? -1.0 : 1.0;
    q[l + m][l + m] = cd(sg * is2, 0.0);
    q[l + m][l - m] = cd(0.0, sg * is2);
  }
  cd ph(1.0, 0.0); const cd mi(0.0, -1.0);
  for (int t = 0; t < l; ++t) ph *= mi;   // (-i)^l
  for (int a = 0; a <= 2 * l; ++a) for (int b = 0; b <= 2 * l; ++b) q[a][b] *= ph;
}

static void w3j_fill(int l1, int l2, int l3, float* outp) {
  double C[5][5][5]; su2_cg(l1, l2, l3, C);
  cd q1[5][5], q2[5][5], q3[5][5];
  qmat(l1, q1); qmat(l2, q2); qmat(l3, q3);
  const int d1 = 2 * l1 + 1, d2 = 2 * l2 + 1, d3 = 2 * l3 + 1;
  double R[5][5][5]; double nrm = 0.0;
  for (int j = 0; j < d1; ++j)
    for (int L = 0; L < d2; ++L)
      for (int m = 0; m < d3; ++m) {
        cd s(0.0, 0.0);
        for (int i = 0; i < d1; ++i)
          for (int k = 0; k < d2; ++k)
            for (int n = 0; n < d3; ++n)
              s += q1[i][j] * q2[k][L] * std::conj(q3[n][m]) * C[i][k][n];
        R[j][L][m] = s.real();
        nrm += s.real() * s.real();
      }
  const double inv = 1.0 / std::sqrt(nrm);
  for (int j = 0; j < d1; ++j)
    for (int L = 0; L < d2; ++L)
      for (int m = 0; m < d3; ++m)
        outp[(j * d2 + L) * d3 + m] = (float)(R[j][L][m] * inv);
}

static void build_cg(CgPack* cg) {
  const int L1[11] = {0,0,0,1,1,1,1,2,2,2,2};
  const int L2[11] = {0,1,2,0,1,1,2,0,1,2,2};
  const int L3[11] = {0,1,2,1,0,2,1,2,1,0,2};
  const int CGO[11]= {0,1,10,35,44,53,98,143,168,213,238};
  for (int p = 0; p < 11; ++p) w3j_fill(L1[p], L2[p], L3[p], &cg->v[CGO[p]]);
}

// ======================= device-side path constants =======================
constexpr int cP_l1[11] = {0,0,0,1,1,1,1,2,2,2,2};
constexpr int cP_l2[11] = {0,1,2,0,1,1,2,0,1,2,2};
constexpr int cP_l3[11] = {0,1,2,1,0,2,1,2,1,0,2};
constexpr int cP_wo[11] = {0,1024,1536,1792,2048,2560,2688,2944,3008,3136,3392};
constexpr int cP_cgo[11]= {0,1,10,35,44,53,98,143,168,213,238};
constexpr int mul_of_l(int l)    { return l == 0 ? 32 : (l == 1 ? 16 : 8); }
constexpr int off_in_of_l(int l) { return l == 0 ? 0  : (l == 1 ? 32 : 80); }
constexpr int off_sh_of_l(int l) { return l == 0 ? 0  : (l == 1 ? 1  : 4); }
constexpr int log2i(int x)       { return x == 32 ? 5 : (x == 16 ? 4 : 3); }

#define HSP 68   // Hs row pad (avoids 8-way write conflicts; 2-way reads are free)

__device__ __forceinline__ float silu_f(float x) { return x / (1.0f + __expf(-x)); }

// one tensor-product path: tmp build -> per-chunk {stage Ws -> reg GEMM -> fused contract}
template<int P>
__device__ void do_path(const CgPack& cg,
                        const float* __restrict__ w3, const float* __restrict__ b3,
                        float (&x1s)[64][124], float (&x2s)[64][13], float* tmpT,
                        float* Ws, float (&Hs)[64][HSP], float (&msg)[64][120])
{
  constexpr int l1 = cP_l1[P], l2 = cP_l2[P], l3 = cP_l3[P];
  constexpr int m1 = mul_of_l(l1), m3 = mul_of_l(l3);
  constexpr int d1 = 2*l1+1, d2 = 2*l2+1, d3 = 2*l3+1;
  constexpr int off1 = off_in_of_l(l1);
  constexpr int off2 = off_sh_of_l(l2);
  constexpr int off3 = off_in_of_l(l3);
  constexpr int wo = cP_wo[P], cgo = cP_cgo[P];
  constexpr float coeff = (l3==0) ? 0.13363062095621219f
                         : (l3==1) ? 0.20412414523193154f
                                   : 0.27950849718747373f;
  constexpr int UB   = (128/m3 < m1) ? (128/m3) : m1;  // u's per chunk
  constexpr int CW   = UB * m3;                         // chunk cols (128 or 64)
  constexpr int NCH  = m1 / UB;                         // chunks
  constexpr int UGR  = UB / 4;                          // u-groups (4 u's per thread)
  constexpr int L2M3 = log2i(m3);
  constexpr int S_IT = (CW * 64) / (4 * NT);            // staging float4s per thread

  const int tid = threadIdx.x;

  // ---- tmp[e,u,k] = sum_{i,j} x1[e,u,i]*x2[e,j]*cg[i,j,k] -> tmpT[(u*d3+k)*64 + e]
  for (int idx = tid; idx < 64 * m1; idx += NT) {
    const int e = idx & 63, u = idx >> 6;
    float t[d3];
    #pragma unroll
    for (int k = 0; k < d3; ++k) t[k] = 0.0f;
    #pragma unroll
    for (int i = 0; i < d1; ++i) {
      const float a = x1s[e][off1 + u*d1 + i];
      #pragma unroll
      for (int j = 0; j < d2; ++j) {
        const float ab = a * x2s[e][off2 + j];
        #pragma unroll
        for (int k = 0; k < d3; ++k) t[k] += ab * cg.v[cgo + (i*d2 + j)*d3 + k];
      }
    }
    #pragma unroll
    for (int k = 0; k < d3; ++k) tmpT[(u*d3 + k)*64 + e] = t[k];
  }
  __syncthreads();

  // GEMM thread roles: 16 edge-quads x m3 v's x UGR u-groups
  const int et   = tid & 15;
  const int rest = tid >> 4;            // [0,32)
  const int v    = rest & (m3 - 1);
  const int ug   = rest >> L2M3;
  const bool act = (ug < UGR);

  float partial[4 * d3];
  #pragma unroll
  for (int i = 0; i < 4 * d3; ++i) partial[i] = 0.0f;

  for (int ch = 0; ch < NCH; ++ch) {
    // ---- stage Ws chunk, v-major: Ws[k*CW + vv*UB + uu] = w3[k][wo + (ch*UB+uu)*m3 + vv]
    #pragma unroll
    for (int s = 0; s < S_IT; ++s) {
      const int f4 = tid + s * NT;
      const int k  = f4 / (CW / 4);
      const int c4 = (f4 % (CW / 4)) * 4;        // col within chunk (u-major), 4 consecutive v's
      const int uu = c4 >> L2M3, v0 = c4 & (m3 - 1);
      const float4 wv = *(const float4*)(w3 + (size_t)k * 3456 + (wo + (ch*UB + uu)*m3 + v0));
      float* dst = Ws + k * CW + uu;
      dst[(v0+0)*UB] = wv.x; dst[(v0+1)*UB] = wv.y;
      dst[(v0+2)*UB] = wv.z; dst[(v0+3)*UB] = wv.w;
    }
    __syncthreads();

    if (act) {
      // ---- reg GEMM: acc[ei][uj] = sum_k h2[k][e]*w3[k][u,v]
      float acc[16];
      #pragma unroll
      for (int i = 0; i < 16; ++i) acc[i] = 0.0f;
      const float* wsp = Ws + v * UB + ug * 4;
      const float* hsp = &Hs[0][0] + et * 4;
      #pragma unroll 4
      for (int k = 0; k < 64; ++k) {
        const float4 wv = *(const float4*)(wsp + k * CW);
        const float4 he = *(const float4*)(hsp + k * HSP);
        acc[ 0] += he.x*wv.x; acc[ 1] += he.x*wv.y; acc[ 2] += he.x*wv.z; acc[ 3] += he.x*wv.w;
        acc[ 4] += he.y*wv.x; acc[ 5] += he.y*wv.y; acc[ 6] += he.y*wv.z; acc[ 7] += he.y*wv.w;
        acc[ 8] += he.z*wv.x; acc[ 9] += he.z*wv.y; acc[10] += he.z*wv.z; acc[11] += he.z*wv.w;
        acc[12] += he.w*wv.x; acc[13] += he.w*wv.y; acc[14] += he.w*wv.z; acc[15] += he.w*wv.w;
      }
      // ---- fused contract into register partial
      #pragma unroll
      for (int uu = 0; uu < 4; ++uu) {
        const int u = ch*UB + ug*4 + uu;
        const float b3v = b3[wo + u*m3 + v];
        #pragma unroll
        for (int k = 0; k < d3; ++k) {
          const float4 t4 = *(const float4*)(tmpT + (u*d3 + k)*64 + et*4);
          partial[0*d3+k] += (acc[ 0+uu] + b3v) * t4.x;
          partial[1*d3+k] += (acc[ 4+uu] + b3v) * t4.y;
          partial[2*d3+k] += (acc[ 8+uu] + b3v) * t4.z;
          partial[3*d3+k] += (acc[12+uu] + b3v) * t4.w;
        }
      }
    }
    __syncthreads();
  }

  // ---- flush partials into msg (LDS float atomics; <=4-way (e,v) is unique per ug-set)
  if (act) {
    #pragma unroll
    for (int ei = 0; ei < 4; ++ei)
      #pragma unroll
      for (int k = 0; k < d3; ++k)
        atomicAdd(&msg[et*4 + ei][off3 + v*d3 + k], coeff * partial[ei*d3 + k]);
  }
}

// ======================= fused MLP + TP + scatter kernel =======================
__global__ __launch_bounds__(NT, 1)
void tp_fused(const float* __restrict__ nf, const int* __restrict__ eidx,
              const float* __restrict__ sh, const float* __restrict__ rad,
              const float* __restrict__ w1, const float* __restrict__ b1,
              const float* __restrict__ w2, const float* __restrict__ b2,
              const float* __restrict__ w3, const float* __restrict__ b3,
              float* __restrict__ agg, const int E, const CgPack cg)
{
  __shared__ float Hs[64][HSP];       // h2: Hs[k][e]
  __shared__ float x1s[64][124];      // gathered node features
  __shared__ float x2s[64][13];       // edge SH
  __shared__ float msg[64][120];      // per-edge message accumulator
  __shared__ float tmpT[160 * 64];    // tmp transposed [(u*d3+k)][e]; aliased as h1T in phase A
  __shared__ float Ws[64 * 128];      // staged w3 chunk, v-major
  __shared__ int   esrc[64], edst[64];

  const int tid = threadIdx.x;
  const int e0  = blockIdx.x * 64;
  float* h1T = tmpT;                  // h1 transposed: h1T[c*64+e]

  // ---- phase A: edge indices, h1 = silu(rad@w1+b1), x2 stage, msg zero
  if (tid < 64)                 esrc[tid]      = eidx[e0 + tid];
  else if (tid < 128)           edst[tid - 64] = eidx[E + e0 + tid - 64];
  for (int idx = tid; idx < 64 * 64; idx += NT) {
    const int c = idx >> 6, e = idx & 63;
    const float4* r4 = (const float4*)(rad + (size_t)(e0 + e) * 8);
    const float4 ra = r4[0], rb = r4[1];
    float a = b1[c];
    a += ra.x * w1[0*64+c] + ra.y * w1[1*64+c] + ra.z * w1[2*64+c] + ra.w * w1[3*64+c];
    a += rb.x * w1[4*64+c] + rb.y * w1[5*64+c] + rb.z * w1[6*64+c] + rb.w * w1[7*64+c];
    h1T[c * 64 + e] = silu_f(a);
  }
  for (int idx = tid; idx < 64 * 9; idx += NT) {
    const int e = idx / 9, j = idx - e * 9;
    x2s[e][j] = sh[(size_t)(e0 + e) * 9 + j];
  }
  __syncthreads();

  // ---- phase B: gather x1 (vectorized), zero msg, h2 = silu(h1@w2+b2) -> Hs[k][e]
  for (int idx = tid; idx < 64 * 30; idx += NT) {
    const int e = idx / 30, q = idx - e * 30;
    *(float4*)(&x1s[e][q * 4]) = *(const float4*)(nf + (size_t)esrc[e] * 120 + q * 4);
    *(float4*)(&msg[e][q * 4]) = make_float4(0.f, 0.f, 0.f, 0.f);
  }
  for (int idx = tid; idx < 64 * 16; idx += NT) {
    const int c = idx >> 4, eq = (idx & 15) * 4;
    float a0 = b2[c], a1 = b2[c], a2 = b2[c], a3 = b2[c];
    #pragma unroll 8
    for (int i = 0; i < 64; ++i) {
      const float wv = w2[i * 64 + c];
      const float4 h4 = *(const float4*)(&h1T[i * 64 + eq]);
      a0 += h4.x * wv; a1 += h4.y * wv; a2 += h4.z * wv; a3 += h4.w * wv;
    }
    *(float4*)(&Hs[c][eq]) = make_float4(silu_f(a0), silu_f(a1), silu_f(a2), silu_f(a3));
  }
  __syncthreads();

  // ---- all 11 tensor-product paths
  do_path<0>(cg, w3, b3, x1s, x2s, tmpT, Ws, Hs, msg);
  do_path<1>(cg, w3, b3, x1s, x2s, tmpT, Ws, Hs, msg);
  do_path<2>(cg, w3, b3, x1s, x2s, tmpT, Ws, Hs, msg);
  do_path<3>(cg, w3, b3, x1s, x2s, tmpT, Ws, Hs, msg);
  do_path<4>(cg, w3, b3, x1s, x2s, tmpT, Ws, Hs, msg);
  do_path<5>(cg, w3, b3, x1s, x2s, tmpT, Ws, Hs, msg);
  do_path<6>(cg, w3, b3, x1s, x2s, tmpT, Ws, Hs, msg);
  do_path<7>(cg, w3, b3, x1s, x2s, tmpT, Ws, Hs, msg);
  do_path<8>(cg, w3, b3, x1s, x2s, tmpT, Ws, Hs, msg);
  do_path<9>(cg, w3, b3, x1s, x2s, tmpT, Ws, Hs, msg);
  do_path<10>(cg, w3, b3, x1s, x2s, tmpT, Ws, Hs, msg);
  __syncthreads();   // msg flushes complete before scatter

  // ---- scatter: agg[dst] += msg
  for (int idx = tid; idx < 64 * 120; idx += NT) {
    const int e = idx / 120, d = idx - e * 120;
    atomicAdd(&agg[(size_t)edst[e] * 120 + d], msg[e][d]);
  }
}

// ======================= self-interaction + residual =======================
__global__ __launch_bounds__(128)
void si_kernel(const float* __restrict__ agg, const float* __restrict__ nf,
               const float* __restrict__ w0, const float* __restrict__ wl1,
               const float* __restrict__ wl2, float* __restrict__ out)
{
  __shared__ float a[120];
  const int n = blockIdx.x, tid = threadIdx.x;
  if (tid < 120) a[tid] = agg[(size_t)n * 120 + tid];
  __syncthreads();
  if (tid >= 120) return;
  float s = 0.0f;
  if (tid < 32) {
    const int v = tid;
    #pragma unroll
    for (int u = 0; u < 32; ++u) s += a[u] * w0[u * 32 + v];
    s *= 0.17677669529663687f;    // 1/sqrt(32)
  } else if (tid < 80) {
    const int r = tid - 32, v = r / 3, k = r - 3 * v;
    #pragma unroll
    for (int u = 0; u < 16; ++u) s += a[32 + u * 3 + k] * wl1[u * 16 + v];
    s *= 0.25f;                   // 1/sqrt(16)
  } else {
    const int r = tid - 80, v = r / 5, k = r - 5 * v;
    #pragma unroll
    for (int u = 0; u < 8; ++u) s += a[80 + u * 5 + k] * wl2[u * 8 + v];
    s *= 0.35355339059327373f;    // 1/sqrt(8)
  }
  out[(size_t)n * 120 + tid] = s + nf[(size_t)n * 120 + tid];
}

// ======================= launch =======================
extern "C" void kernel_launch(void* const* d_in, const int* in_sizes, int n_in,
                              void* d_out, int out_size, void* d_ws, size_t ws_size,
                              hipStream_t stream) {
  const float* nf  = (const float*)d_in[0];
  const int*   ei  = (const int*)  d_in[1];
  const float* sh  = (const float*)d_in[2];
  const float* rad = (const float*)d_in[3];
  const float* w1  = (const float*)d_in[4];
  const float* b1  = (const float*)d_in[5];
  const float* w2  = (const float*)d_in[6];
  const float* b2  = (const float*)d_in[7];
  const float* w3  = (const float*)d_in[8];
  const float* b3  = (const float*)d_in[9];
  const float* si0 = (const float*)d_in[10];
  const float* si1 = (const float*)d_in[11];
  const float* si2 = (const float*)d_in[12];
  float* out = (float*)d_out;

  const int N = in_sizes[0] / 120;
  const int E = in_sizes[2] / 9;

  float* agg = (float*)d_ws;
  hipMemsetAsync(agg, 0, (size_t)N * 120 * sizeof(float), stream);

  CgPack cg;
  build_cg(&cg);

  tp_fused<<<E / 64, NT, 0, stream>>>(nf, ei, sh, rad, w1, b1, w2, b2, w3, b3, agg, E, cg);
  si_kernel<<<N, 128, 0, stream>>>(agg, nf, si0, si1, si2, out);
}

// Round 3
// 367.425 us; speedup vs baseline: 2.8730x; 1.5927x over previous
//
#include <hip/hip_runtime.h>
#include <hip/hip_bf16.h>
#include <cmath>
#include <complex>

#define NT 512

typedef __bf16 bf16x8 __attribute__((ext_vector_type(8)));
typedef float  f32x4  __attribute__((ext_vector_type(4)));

struct CgPack { float v[363]; };

// ======================= host-side Wigner 3j (e3nn convention) =======================
static double factd(int n) { double r = 1.0; for (int i = 2; i <= n; ++i) r *= i; return r; }

static void su2_cg(int j1, int j2, int j3, double C[5][5][5]) {
  for (int a = 0; a < 5; ++a) for (int b = 0; b < 5; ++b) for (int c = 0; c < 5; ++c) C[a][b][c] = 0.0;
  for (int m1 = -j1; m1 <= j1; ++m1)
    for (int m2 = -j2; m2 <= j2; ++m2) {
      int m3 = m1 + m2;
      if (m3 < -j3 || m3 > j3) continue;
      int vmin = -j1 + j2 + m3; if (-j1 + m1 > vmin) vmin = -j1 + m1; if (vmin < 0) vmin = 0;
      int vmax = j2 + j3 + m1; if (j3 - j1 + j2 < vmax) vmax = j3 - j1 + j2; if (j3 + m3 < vmax) vmax = j3 + m3;
      double c = std::sqrt((2.0 * j3 + 1.0) *
            factd(j3 + j1 - j2) * factd(j3 - j1 + j2) * factd(j1 + j2 - j3) * factd(j3 + m3) * factd(j3 - m3) /
            (factd(j1 + j2 + j3 + 1) * factd(j1 - m1) * factd(j1 + m1) * factd(j2 - m2) * factd(j2 + m2)));
      double S = 0.0;
      for (int v = vmin; v <= vmax; ++v) {
        double t = factd(j2 + j3 + m1 - v) * factd(j1 - m1 + v) /
                   (factd(v) * factd(j3 - j1 + j2 - v) * factd(j3 + m3 - v) * factd(v + j1 - j2 - m3));
        S += (((v + j2 + m2) & 1) ? -t : t);
      }
      C[j1 + m1][j2 + m2][j3 + m3] = c * S;
    }
}

typedef std::complex<double> cd;
static void qmat(int l, cd q[5][5]) {
  for (int a = 0; a < 5; ++a) for (int b = 0; b < 5; ++b) q[a][b] = cd(0.0, 0.0);
  const double is2 = 1.0 / std::sqrt(2.0);
  for (int m = -l; m < 0; ++m) { q[l + m][l - m] = cd(is2, 0.0); q[l + m][l + m] = cd(0.0, -is2); }
  q[l][l] = cd(1.0, 0.0);
  for (int m = 1; m <= l; ++m) {
    double sg = (m & 1) ? -1.0 : 1.0;
    q[l + m][l + m] = cd(sg * is2, 0.0);
    q[l + m][l - m] = cd(0.0, sg * is2);
  }
  cd ph(1.0, 0.0); const cd mi(0.0, -1.0);
  for (int t = 0; t < l; ++t) ph *= mi;   // (-i)^l
  for (int a = 0; a <= 2 * l; ++a) for (int b = 0; b <= 2 * l; ++b) q[a][b] *= ph;
}

static void w3j_fill(int l1, int l2, int l3, float* outp) {
  double C[5][5][5]; su2_cg(l1, l2, l3, C);
  cd q1[5][5], q2[5][5], q3[5][5];
  qmat(l1, q1); qmat(l2, q2); qmat(l3, q3);
  const int d1 = 2 * l1 + 1, d2 = 2 * l2 + 1, d3 = 2 * l3 + 1;
  double R[5][5][5]; double nrm = 0.0;
  for (int j = 0; j < d1; ++j)
    for (int L = 0; L < d2; ++L)
      for (int m = 0; m < d3; ++m) {
        cd s(0.0, 0.0);
        for (int i = 0; i < d1; ++i)
          for (int k = 0; k < d2; ++k)
            for (int n = 0; n < d3; ++n)
              s += q1[i][j] * q2[k][L] * std::conj(q3[n][m]) * C[i][k][n];
        R[j][L][m] = s.real();
        nrm += s.real() * s.real();
      }
  const double inv = 1.0 / std::sqrt(nrm);
  for (int j = 0; j < d1; ++j)
    for (int L = 0; L < d2; ++L)
      for (int m = 0; m < d3; ++m)
        outp[(j * d2 + L) * d3 + m] = (float)(R[j][L][m] * inv);
}

static void build_cg(CgPack* cg) {
  const int L1[11] = {0,0,0,1,1,1,1,2,2,2,2};
  const int L2[11] = {0,1,2,0,1,1,2,0,1,2,2};
  const int L3[11] = {0,1,2,1,0,2,1,2,1,0,2};
  const int CGO[11]= {0,1,10,35,44,53,98,143,168,213,238};
  for (int p = 0; p < 11; ++p) w3j_fill(L1[p], L2[p], L3[p], &cg->v[CGO[p]]);
}

// ======================= device-side path constants =======================
constexpr int cP_l1[11] = {0,0,0,1,1,1,1,2,2,2,2};
constexpr int cP_l2[11] = {0,1,2,0,1,1,2,0,1,2,2};
constexpr int cP_l3[11] = {0,1,2,1,0,2,1,2,1,0,2};
constexpr int cP_wo[11] = {0,1024,1536,1792,2048,2560,2688,2944,3008,3136,3392};
constexpr int cP_cgo[11]= {0,1,10,35,44,53,98,143,168,213,238};
constexpr int mul_of_l(int l)    { return l == 0 ? 32 : (l == 1 ? 16 : 8); }
constexpr int off_in_of_l(int l) { return l == 0 ? 0  : (l == 1 ? 32 : 80); }
constexpr int off_sh_of_l(int l) { return l == 0 ? 0  : (l == 1 ? 1  : 4); }
constexpr int log2i(int x)       { return x == 32 ? 5 : (x == 16 ? 4 : 3); }

__device__ __forceinline__ float silu_f(float x) { return x / (1.0f + __expf(-x)); }

// one tensor-product path:
//   tmp build -> per 128-col chunk { MFMA weight-GEMM -> Cs ; contract Cs x tmpT -> partial }
template<int P>
__device__ void do_path(const CgPack& cg, const __bf16* __restrict__ w3b,
                        const float* __restrict__ b3,
                        float (&x1s)[64][124], float (&x2s)[64][13],
                        float* tmpT, float (&Cs)[64][133],
                        float (&msg)[64][121], const bf16x8 (&afrag)[4][2])
{
  constexpr int l1 = cP_l1[P], l2 = cP_l2[P], l3 = cP_l3[P];
  constexpr int m1 = mul_of_l(l1), m3 = mul_of_l(l3);
  constexpr int d1 = 2*l1+1, d2 = 2*l2+1, d3 = 2*l3+1;
  constexpr int off1 = off_in_of_l(l1);
  constexpr int off2 = off_sh_of_l(l2);
  constexpr int off3 = off_in_of_l(l3);
  constexpr int wo = cP_wo[P], cgo = cP_cgo[P];
  constexpr float coeff = (l3==0) ? 0.13363062095621219f
                         : (l3==1) ? 0.20412414523193154f
                                   : 0.27950849718747373f;
  constexpr int cols = m1 * m3;
  constexpr int CW   = (cols < 128) ? cols : 128;   // chunk width: 128 or 64
  constexpr int NCH  = cols / CW;
  constexpr int UB   = CW / m3;                     // u's per chunk
  constexpr int UGR  = UB / 4;                      // u-groups of 4
  constexpr int L2M3 = log2i(m3);
  constexpr int NCT  = CW / 16;                     // col-tiles per chunk: 8 or 4
  constexpr int NB   = (NCT == 8) ? 4 : 2;          // edge-bands per wave

  const int tid  = threadIdx.x;
  const int lane = tid & 63, wid = tid >> 6;
  const int lr   = lane >> 4, lc = lane & 15;
  const int ct   = (NCT == 8) ? wid : (wid & 3);
  const int b0   = (NCT == 8) ? 0 : ((wid < 4) ? 0 : 2);

  // ---- prefetch B-frags for chunk 0 (hidden under tmp build)
  bf16x8 bA, bB, bA2, bB2;
  { const __bf16* p = w3b + (size_t)(wo + ct*16 + lc) * 64 + lr*8;
    bA = *(const bf16x8*)p; bB = *(const bf16x8*)(p + 32); }

  // ---- tmp[e,u,k] = sum_{i,j} x1[e,u,i]*x2[e,j]*cg[i,j,k] -> tmpT[(u*d3+k)*64 + e]
  for (int idx = tid; idx < 64 * m1; idx += NT) {
    const int e = idx & 63, u = idx >> 6;
    float t[d3];
    #pragma unroll
    for (int k = 0; k < d3; ++k) t[k] = 0.0f;
    #pragma unroll
    for (int i = 0; i < d1; ++i) {
      const float a = x1s[e][off1 + u*d1 + i];
      #pragma unroll
      for (int j = 0; j < d2; ++j) {
        const float ab = a * x2s[e][off2 + j];
        #pragma unroll
        for (int k = 0; k < d3; ++k) t[k] += ab * cg.v[cgo + (i*d2 + j)*d3 + k];
      }
    }
    #pragma unroll
    for (int k = 0; k < d3; ++k) tmpT[(u*d3 + k)*64 + e] = t[k];
  }

  // contract thread roles
  const int et   = tid & 15;
  const int rest = tid >> 4;
  const int v    = rest & (m3 - 1);
  const int ug   = rest >> L2M3;
  const bool act = (ug < UGR);

  float partial[4 * d3];
  #pragma unroll
  for (int i = 0; i < 4 * d3; ++i) partial[i] = 0.0f;

  for (int ch = 0; ch < NCH; ++ch) {
    // ---- MFMA GEMM: D[e][col] = sum_k h2[e,k] * w3[k,col]
    f32x4 dacc[NB];
    #pragma unroll
    for (int b = 0; b < NB; ++b) {
      f32x4 d = {0.f, 0.f, 0.f, 0.f};
      d = __builtin_amdgcn_mfma_f32_16x16x32_bf16(afrag[b0+b][0], bA, d, 0, 0, 0);
      d = __builtin_amdgcn_mfma_f32_16x16x32_bf16(afrag[b0+b][1], bB, d, 0, 0, 0);
      dacc[b] = d;
    }
    if (ch + 1 < NCH) {   // prefetch next chunk's B-frags (overlaps contract below)
      const __bf16* p = w3b + (size_t)(wo + (ch+1)*CW + ct*16 + lc) * 64 + lr*8;
      bA2 = *(const bf16x8*)p; bB2 = *(const bf16x8*)(p + 32);
    }
    // D -> Cs: row = band*16 + lr*4 + r (edge), col = ct*16 + lc
    #pragma unroll
    for (int b = 0; b < NB; ++b)
      #pragma unroll
      for (int r = 0; r < 4; ++r)
        Cs[(b0+b)*16 + lr*4 + r][ct*16 + lc] = dacc[b][r];
    __syncthreads();

    // ---- contract: partial[e][k] += (Cs[e][u*m3+v]+b3) * tmp[e,u,k]
    if (act) {
      #pragma unroll
      for (int uu = 0; uu < 4; ++uu) {
        const int ul = ug*4 + uu;
        const int u  = ch*UB + ul;
        const float b3v = b3[wo + u*m3 + v];
        const float wa = Cs[et*4+0][ul*m3+v] + b3v;
        const float wb = Cs[et*4+1][ul*m3+v] + b3v;
        const float wc = Cs[et*4+2][ul*m3+v] + b3v;
        const float wd = Cs[et*4+3][ul*m3+v] + b3v;
        #pragma unroll
        for (int k = 0; k < d3; ++k) {
          const float4 t4 = *(const float4*)(tmpT + (u*d3 + k)*64 + et*4);
          partial[0*d3+k] += wa * t4.x;
          partial[1*d3+k] += wb * t4.y;
          partial[2*d3+k] += wc * t4.z;
          partial[3*d3+k] += wd * t4.w;
        }
      }
    }
    __syncthreads();   // Cs free for next chunk / tmpT free at path end
    if (ch + 1 < NCH) { bA = bA2; bB = bB2; }
  }

  // ---- flush partials into msg (LDS atomics; msg pad 121 -> 2-way banks)
  if (act) {
    #pragma unroll
    for (int ei = 0; ei < 4; ++ei)
      #pragma unroll
      for (int k = 0; k < d3; ++k)
        atomicAdd(&msg[et*4 + ei][off3 + v*d3 + k], coeff * partial[ei*d3 + k]);
  }
  __syncthreads();
}

// ======================= w3 -> bf16 (col-major, K-contiguous) =======================
__global__ __launch_bounds__(256)
void conv_w3(const float* __restrict__ w3, __bf16* __restrict__ w3b, const int n) {
  const int idx = blockIdx.x * 256 + threadIdx.x;
  if (idx >= n) return;
  const int k = idx / 3456, col = idx - k * 3456;
  w3b[(size_t)col * 64 + k] = (__bf16)w3[idx];
}

// ======================= fused MLP + TP + scatter kernel =======================
__global__ __launch_bounds__(NT, 2)
void tp_fused(const float* __restrict__ nf, const int* __restrict__ eidx,
              const float* __restrict__ sh, const float* __restrict__ rad,
              const float* __restrict__ w1, const float* __restrict__ b1,
              const float* __restrict__ w2, const float* __restrict__ b2,
              const __bf16* __restrict__ w3b, const float* __restrict__ b3,
              float* __restrict__ agg, const int E, const CgPack cg)
{
  __shared__ float x1s[64][124];      // gathered node features
  __shared__ float x2s[64][13];       // edge SH
  __shared__ float msg[64][121];      // per-edge message accumulator (pad 121)
  __shared__ float tmpT[160 * 64];    // tmp transposed [(u*d3+k)][e]; aliased as h1T in phase A
  __shared__ float Cs[64][133];       // weight chunk [e][col_local] (pad 133)
  __shared__ __bf16 h2b[64 * 64];     // h2 bf16, [e][k] K-contiguous
  __shared__ int   esrc[64], edst[64];

  const int tid  = threadIdx.x;
  const int lane = tid & 63;
  const int lr   = lane >> 4, lc = lane & 15;
  const int e0   = blockIdx.x * 64;
  float* h1T = tmpT;                  // h1 transposed: h1T[c*64+e]

  // ---- phase A: edge indices, h1 = silu(rad@w1+b1), x2 stage
  if (tid < 64)                 esrc[tid]      = eidx[e0 + tid];
  else if (tid < 128)           edst[tid - 64] = eidx[E + e0 + tid - 64];
  for (int idx = tid; idx < 64 * 64; idx += NT) {
    const int c = idx >> 6, e = idx & 63;
    const float4* r4 = (const float4*)(rad + (size_t)(e0 + e) * 8);
    const float4 ra = r4[0], rb = r4[1];
    float a = b1[c];
    a += ra.x * w1[0*64+c] + ra.y * w1[1*64+c] + ra.z * w1[2*64+c] + ra.w * w1[3*64+c];
    a += rb.x * w1[4*64+c] + rb.y * w1[5*64+c] + rb.z * w1[6*64+c] + rb.w * w1[7*64+c];
    h1T[c * 64 + e] = silu_f(a);
  }
  for (int idx = tid; idx < 64 * 9; idx += NT) {
    const int e = idx / 9, j = idx - e * 9;
    x2s[e][j] = sh[(size_t)(e0 + e) * 9 + j];
  }
  for (int idx = tid; idx < 64 * 121; idx += NT) (&msg[0][0])[idx] = 0.0f;
  __syncthreads();

  // ---- phase B: gather x1 (vectorized), h2 = silu(h1@w2+b2) -> h2b[e][k] bf16
  for (int idx = tid; idx < 64 * 30; idx += NT) {
    const int e = idx / 30, q = idx - e * 30;
    *(float4*)(&x1s[e][q * 4]) = *(const float4*)(nf + (size_t)esrc[e] * 120 + q * 4);
  }
  for (int idx = tid; idx < 64 * 16; idx += NT) {
    const int c = idx >> 4, eq = (idx & 15) * 4;
    float a0 = b2[c], a1 = b2[c], a2 = b2[c], a3 = b2[c];
    #pragma unroll 8
    for (int i = 0; i < 64; ++i) {
      const float wv = w2[i * 64 + c];
      const float4 h4 = *(const float4*)(&h1T[i * 64 + eq]);
      a0 += h4.x * wv; a1 += h4.y * wv; a2 += h4.z * wv; a3 += h4.w * wv;
    }
    h2b[(eq+0)*64 + c] = (__bf16)silu_f(a0);
    h2b[(eq+1)*64 + c] = (__bf16)silu_f(a1);
    h2b[(eq+2)*64 + c] = (__bf16)silu_f(a2);
    h2b[(eq+3)*64 + c] = (__bf16)silu_f(a3);
  }
  __syncthreads();

  // ---- A-fragments: lane holds h2[e = band*16 + lc][k = kb*32 + lr*8 + j]
  bf16x8 afrag[4][2];
  #pragma unroll
  for (int b = 0; b < 4; ++b)
    #pragma unroll
    for (int kb = 0; kb < 2; ++kb)
      afrag[b][kb] = *(const bf16x8*)(h2b + (b*16 + lc)*64 + kb*32 + lr*8);

  // ---- all 11 tensor-product paths
  do_path< 0>(cg, w3b, b3, x1s, x2s, tmpT, Cs, msg, afrag);
  do_path< 1>(cg, w3b, b3, x1s, x2s, tmpT, Cs, msg, afrag);
  do_path< 2>(cg, w3b, b3, x1s, x2s, tmpT, Cs, msg, afrag);
  do_path< 3>(cg, w3b, b3, x1s, x2s, tmpT, Cs, msg, afrag);
  do_path< 4>(cg, w3b, b3, x1s, x2s, tmpT, Cs, msg, afrag);
  do_path< 5>(cg, w3b, b3, x1s, x2s, tmpT, Cs, msg, afrag);
  do_path< 6>(cg, w3b, b3, x1s, x2s, tmpT, Cs, msg, afrag);
  do_path< 7>(cg, w3b, b3, x1s, x2s, tmpT, Cs, msg, afrag);
  do_path< 8>(cg, w3b, b3, x1s, x2s, tmpT, Cs, msg, afrag);
  do_path< 9>(cg, w3b, b3, x1s, x2s, tmpT, Cs, msg, afrag);
  do_path<10>(cg, w3b, b3, x1s, x2s, tmpT, Cs, msg, afrag);

  // ---- scatter: agg[dst] += msg  (do_path<10> ended with a barrier)
  for (int idx = tid; idx < 64 * 120; idx += NT) {
    const int e = idx / 120, d = idx - e * 120;
    atomicAdd(&agg[(size_t)edst[e] * 120 + d], msg[e][d]);
  }
}

// ======================= self-interaction + residual =======================
__global__ __launch_bounds__(128)
void si_kernel(const float* __restrict__ agg, const float* __restrict__ nf,
               const float* __restrict__ w0, const float* __restrict__ wl1,
               const float* __restrict__ wl2, float* __restrict__ out)
{
  __shared__ float a[120];
  const int n = blockIdx.x, tid = threadIdx.x;
  if (tid < 120) a[tid] = agg[(size_t)n * 120 + tid];
  __syncthreads();
  if (tid >= 120) return;
  float s = 0.0f;
  if (tid < 32) {
    const int v = tid;
    #pragma unroll
    for (int u = 0; u < 32; ++u) s += a[u] * w0[u * 32 + v];
    s *= 0.17677669529663687f;    // 1/sqrt(32)
  } else if (tid < 80) {
    const int r = tid - 32, v = r / 3, k = r - 3 * v;
    #pragma unroll
    for (int u = 0; u < 16; ++u) s += a[32 + u * 3 + k] * wl1[u * 16 + v];
    s *= 0.25f;                   // 1/sqrt(16)
  } else {
    const int r = tid - 80, v = r / 5, k = r - 5 * v;
    #pragma unroll
    for (int u = 0; u < 8; ++u) s += a[80 + u * 5 + k] * wl2[u * 8 + v];
    s *= 0.35355339059327373f;    // 1/sqrt(8)
  }
  out[(size_t)n * 120 + tid] = s + nf[(size_t)n * 120 + tid];
}

// ======================= launch =======================
extern "C" void kernel_launch(void* const* d_in, const int* in_sizes, int n_in,
                              void* d_out, int out_size, void* d_ws, size_t ws_size,
                              hipStream_t stream) {
  const float* nf  = (const float*)d_in[0];
  const int*   ei  = (const int*)  d_in[1];
  const float* sh  = (const float*)d_in[2];
  const float* rad = (const float*)d_in[3];
  const float* w1  = (const float*)d_in[4];
  const float* b1  = (const float*)d_in[5];
  const float* w2  = (const float*)d_in[6];
  const float* b2  = (const float*)d_in[7];
  const float* w3  = (const float*)d_in[8];
  const float* b3  = (const float*)d_in[9];
  const float* si0 = (const float*)d_in[10];
  const float* si1 = (const float*)d_in[11];
  const float* si2 = (const float*)d_in[12];
  float* out = (float*)d_out;

  const int N = in_sizes[0] / 120;
  const int E = in_sizes[2] / 9;
  const int W3N = in_sizes[8];          // 64*3456

  float*  agg = (float*)d_ws;
  __bf16* w3b = (__bf16*)((char*)d_ws + (size_t)N * 120 * sizeof(float));
  hipMemsetAsync(agg, 0, (size_t)N * 120 * sizeof(float), stream);

  CgPack cg;
  build_cg(&cg);

  conv_w3<<<(W3N + 255) / 256, 256, 0, stream>>>(w3, w3b, W3N);
  tp_fused<<<E / 64, NT, 0, stream>>>(nf, ei, sh, rad, w1, b1, w2, b2, w3b, b3, agg, E, cg);
  si_kernel<<<N, 128, 0, stream>>>(agg, nf, si0, si1, si2, out);
}

// Round 5
// 279.469 us; speedup vs baseline: 3.7772x; 1.3147x over previous
//
#include <hip/hip_runtime.h>
#include <hip/hip_bf16.h>
#include <cmath>
#include <complex>

#define NT 512

typedef __bf16 bf16x8 __attribute__((ext_vector_type(8)));
typedef float  f32x4  __attribute__((ext_vector_type(4)));

struct CgPack { float v[363]; };

// ======================= host-side Wigner 3j (e3nn convention) =======================
static double factd(int n) { double r = 1.0; for (int i = 2; i <= n; ++i) r *= i; return r; }

static void su2_cg(int j1, int j2, int j3, double C[5][5][5]) {
  for (int a = 0; a < 5; ++a) for (int b = 0; b < 5; ++b) for (int c = 0; c < 5; ++c) C[a][b][c] = 0.0;
  for (int m1 = -j1; m1 <= j1; ++m1)
    for (int m2 = -j2; m2 <= j2; ++m2) {
      int m3 = m1 + m2;
      if (m3 < -j3 || m3 > j3) continue;
      int vmin = -j1 + j2 + m3; if (-j1 + m1 > vmin) vmin = -j1 + m1; if (vmin < 0) vmin = 0;
      int vmax = j2 + j3 + m1; if (j3 - j1 + j2 < vmax) vmax = j3 - j1 + j2; if (j3 + m3 < vmax) vmax = j3 + m3;
      double c = std::sqrt((2.0 * j3 + 1.0) *
            factd(j3 + j1 - j2) * factd(j3 - j1 + j2) * factd(j1 + j2 - j3) * factd(j3 + m3) * factd(j3 - m3) /
            (factd(j1 + j2 + j3 + 1) * factd(j1 - m1) * factd(j1 + m1) * factd(j2 - m2) * factd(j2 + m2)));
      double S = 0.0;
      for (int v = vmin; v <= vmax; ++v) {
        double t = factd(j2 + j3 + m1 - v) * factd(j1 - m1 + v) /
                   (factd(v) * factd(j3 - j1 + j2 - v) * factd(j3 + m3 - v) * factd(v + j1 - j2 - m3));
        S += (((v + j2 + m2) & 1) ? -t : t);
      }
      C[j1 + m1][j2 + m2][j3 + m3] = c * S;
    }
}

typedef std::complex<double> cd;
static void qmat(int l, cd q[5][5]) {
  for (int a = 0; a < 5; ++a) for (int b = 0; b < 5; ++b) q[a][b] = cd(0.0, 0.0);
  const double is2 = 1.0 / std::sqrt(2.0);
  for (int m = -l; m < 0; ++m) { q[l + m][l - m] = cd(is2, 0.0); q[l + m][l + m] = cd(0.0, -is2); }
  q[l][l] = cd(1.0, 0.0);
  for (int m = 1; m <= l; ++m) {
    double sg = (m & 1) ? -1.0 : 1.0;
    q[l + m][l + m] = cd(sg * is2, 0.0);
    q[l + m][l - m] = cd(0.0, sg * is2);
  }
  cd ph(1.0, 0.0); const cd mi(0.0, -1.0);
  for (int t = 0; t < l; ++t) ph *= mi;   // (-i)^l
  for (int a = 0; a <= 2 * l; ++a) for (int b = 0; b <= 2 * l; ++b) q[a][b] *= ph;
}

static void w3j_fill(int l1, int l2, int l3, float* outp) {
  double C[5][5][5]; su2_cg(l1, l2, l3, C);
  cd q1[5][5], q2[5][5], q3[5][5];
  qmat(l1, q1); qmat(l2, q2); qmat(l3, q3);
  const int d1 = 2 * l1 + 1, d2 = 2 * l2 + 1, d3 = 2 * l3 + 1;
  double R[5][5][5]; double nrm = 0.0;
  for (int j = 0; j < d1; ++j)
    for (int L = 0; L < d2; ++L)
      for (int m = 0; m < d3; ++m) {
        cd s(0.0, 0.0);
        for (int i = 0; i < d1; ++i)
          for (int k = 0; k < d2; ++k)
            for (int n = 0; n < d3; ++n)
              s += q1[i][j] * q2[k][L] * std::conj(q3[n][m]) * C[i][k][n];
        R[j][L][m] = s.real();
        nrm += s.real() * s.real();
      }
  const double inv = 1.0 / std::sqrt(nrm);
  for (int j = 0; j < d1; ++j)
    for (int L = 0; L < d2; ++L)
      for (int m = 0; m < d3; ++m)
        outp[(j * d2 + L) * d3 + m] = (float)(R[j][L][m] * inv);
}

static void build_cg(CgPack* cg) {
  const int L1[11] = {0,0,0,1,1,1,1,2,2,2,2};
  const int L2[11] = {0,1,2,0,1,1,2,0,1,2,2};
  const int L3[11] = {0,1,2,1,0,2,1,2,1,0,2};
  const int CGO[11]= {0,1,10,35,44,53,98,143,168,213,238};
  for (int p = 0; p < 11; ++p) w3j_fill(L1[p], L2[p], L3[p], &cg->v[CGO[p]]);
}

// ======================= device-side path constants =======================
constexpr int cP_l1[11] = {0,0,0,1,1,1,1,2,2,2,2};
constexpr int cP_l2[11] = {0,1,2,0,1,1,2,0,1,2,2};
constexpr int cP_l3[11] = {0,1,2,1,0,2,1,2,1,0,2};
constexpr int cP_wo[11] = {0,1024,1536,1792,2048,2560,2688,2944,3008,3136,3392};
constexpr int cP_cgo[11]= {0,1,10,35,44,53,98,143,168,213,238};
constexpr int mul_of_l(int l)    { return l == 0 ? 32 : (l == 1 ? 16 : 8); }
constexpr int off_in_of_l(int l) { return l == 0 ? 0  : (l == 1 ? 32 : 80); }
constexpr int off_sh_of_l(int l) { return l == 0 ? 0  : (l == 1 ? 1  : 4); }

__device__ __forceinline__ float silu_f(float x) { return x / (1.0f + __expf(-x)); }

// one 16-col x 16-edge MFMA tile + immediate register contract
template<int wo, int m3, int d3>
__device__ __forceinline__ void tile_mm(
    const __bf16* __restrict__ w3b, const float* __restrict__ b3,
    const float* tmpw, const bf16x8 hB0, const bf16x8 hB1,
    const int u0, const int tt, const int uu, const int lr, const int lc,
    float (&acc)[4*d3])
{
  const int cb = wo + u0*m3 + tt*16;                    // global col base of tile
  const __bf16* ap = w3b + (size_t)(cb + lc)*64 + lr*8; // A = w3 tile (col=lc row of A)
  const bf16x8 a0 = *(const bf16x8*)ap;                 // k = lr*8..+8
  const bf16x8 a1 = *(const bf16x8*)(ap + 32);          // k = 32+lr*8..+8
  f32x4 dd = {0.f, 0.f, 0.f, 0.f};
  dd = __builtin_amdgcn_mfma_f32_16x16x32_bf16(a0, hB0, dd, 0, 0, 0);
  dd = __builtin_amdgcn_mfma_f32_16x16x32_bf16(a1, hB1, dd, 0, 0, 0);
  // D[w3col = lr*4+r][edge = lc]
  float tv[d3];
  #pragma unroll
  for (int k = 0; k < d3; ++k) tv[k] = tmpw[(uu*d3 + k)*16 + lc];
  #pragma unroll
  for (int r = 0; r < 4; ++r) {
    const float w = dd[r] + b3[cb + lr*4 + r];
    #pragma unroll
    for (int k = 0; k < d3; ++k) acc[r*d3 + k] += w * tv[k];
  }
}

// one tensor-product path, fully wave-local (no block barriers)
template<int P>
__device__ __forceinline__ void wave_path(
    const CgPack& cg, const __bf16* __restrict__ w3b, const float* __restrict__ b3,
    const float* __restrict__ nf, const int* esrc, float (&x2s)[64][13],
    float* tmpw, float (&msg)[64][121],
    const bf16x8 hB0, const bf16x8 hB1, const int g, const int lane)
{
  constexpr int l1 = cP_l1[P], l2 = cP_l2[P], l3 = cP_l3[P];
  constexpr int m1 = mul_of_l(l1), m3 = mul_of_l(l3);
  constexpr int d1 = 2*l1+1, d2 = 2*l2+1, d3 = 2*l3+1;
  constexpr int off1 = off_in_of_l(l1);
  constexpr int off2 = off_sh_of_l(l2);
  constexpr int off3 = off_in_of_l(l3);
  constexpr int wo = cP_wo[P], cgo = cP_cgo[P];
  constexpr float coeff = (l3==0) ? 0.13363062095621219f
                         : (l3==1) ? 0.20412414523193154f
                                   : 0.27950849718747373f;
  constexpr int UBLK = (m1 < 16) ? m1 : 16;     // u's per tmp block (tmp rows <= 80)
  constexpr int NUB  = m1 / UBLK;
  constexpr int NTIL = UBLK * m3 / 16;          // 16-col tiles per u-block

  const int lr = lane >> 4, lc = lane & 15;
  const int e  = g*16 + lc;                     // this lane's edge (block-local)

  float accA[4*d3];
  float accB[(m3==32) ? 4 : 1];
  #pragma unroll
  for (int i = 0; i < 4*d3; ++i) accA[i] = 0.0f;
  #pragma unroll
  for (int i = 0; i < ((m3==32) ? 4 : 1); ++i) accB[i] = 0.0f;

  for (int ub = 0; ub < NUB; ++ub) {
    const int u0 = ub * UBLK;
    // ---- tmp build (wave-local LDS): tmpw[(uu*d3+k)*16 + e] for uu in [0,UBLK)
    #pragma unroll
    for (int it = 0; it < UBLK/4; ++it) {
      const int idx = (it << 6) + lane;
      const int te = idx & 15, uu = idx >> 4;
      const float* xr = nf + (size_t)esrc[g*16 + te] * 120 + (off1 + (u0 + uu)*d1);
      float t[d3];
      #pragma unroll
      for (int k = 0; k < d3; ++k) t[k] = 0.0f;
      #pragma unroll
      for (int i = 0; i < d1; ++i) {
        const float a = xr[i];
        #pragma unroll
        for (int j = 0; j < d2; ++j) {
          const float ab = a * x2s[g*16 + te][off2 + j];
          #pragma unroll
          for (int k = 0; k < d3; ++k) t[k] += ab * cg.v[cgo + (i*d2 + j)*d3 + k];
        }
      }
      #pragma unroll
      for (int k = 0; k < d3; ++k) tmpw[(uu*d3 + k)*16 + te] = t[k];
    }
    // (same-wave LDS producer/consumer: compiler orders via lgkmcnt; no barrier)

    // ---- tile loop: MFMA + immediate contract
    if constexpr (m3 == 32) {
      for (int tt = 0; tt < NTIL; tt += 2) {
        tile_mm<wo, m3, d3>(w3b, b3, tmpw, hB0, hB1, u0, tt,   tt>>1, lr, lc, accA);
        tile_mm<wo, m3, d3>(w3b, b3, tmpw, hB0, hB1, u0, tt+1, tt>>1, lr, lc, accB);
      }
    } else {
      for (int tt = 0; tt < NTIL; ++tt) {
        const int uu = (m3 == 16) ? tt : (2*tt + (lr >> 1));
        tile_mm<wo, m3, d3>(w3b, b3, tmpw, hB0, hB1, u0, tt, uu, lr, lc, accA);
      }
    }
  }

  // ---- flush into msg (LDS atomics; cross-wave overlap possible)
  if constexpr (m3 == 16) {
    #pragma unroll
    for (int r = 0; r < 4; ++r)
      #pragma unroll
      for (int k = 0; k < d3; ++k)
        atomicAdd(&msg[e][off3 + (lr*4 + r)*d3 + k], coeff * accA[r*d3 + k]);
  } else if constexpr (m3 == 8) {
    #pragma unroll
    for (int i = 0; i < 4*d3; ++i) accA[i] += __shfl_xor(accA[i], 32, 64);
    if (lane < 32) {   // lr in {0,1}: v = lr*4+r covers 0..7
      #pragma unroll
      for (int r = 0; r < 4; ++r)
        #pragma unroll
        for (int k = 0; k < d3; ++k)
          atomicAdd(&msg[e][off3 + (lr*4 + r)*d3 + k], coeff * accA[r*d3 + k]);
    }
  } else {  // m3 == 32, d3 == 1
    #pragma unroll
    for (int r = 0; r < 4; ++r) {
      atomicAdd(&msg[e][off3 +      lr*4 + r], coeff * accA[r]);
      atomicAdd(&msg[e][off3 + 16 + lr*4 + r], coeff * accB[r]);
    }
  }
}

// ======================= w3 -> bf16 (col-major, K-contiguous) =======================
__global__ __launch_bounds__(256)
void conv_w3(const float* __restrict__ w3, __bf16* __restrict__ w3b, const int n) {
  const int idx = blockIdx.x * 256 + threadIdx.x;
  if (idx >= n) return;
  const int k = idx / 3456, col = idx - k * 3456;
  w3b[(size_t)col * 64 + k] = (__bf16)w3[idx];
}

// ======================= fused MLP + TP + scatter kernel =======================
__global__ __launch_bounds__(NT, 4)
void tp_fused(const float* __restrict__ nf, const int* __restrict__ eidx,
              const float* __restrict__ sh, const float* __restrict__ rad,
              const float* __restrict__ w1, const float* __restrict__ b1,
              const float* __restrict__ w2, const float* __restrict__ b2,
              const __bf16* __restrict__ w3b, const float* __restrict__ b3,
              float* __restrict__ agg, const int E, const CgPack cg)
{
  __shared__ float msg[64][121];      // per-edge message accumulator (30.9 KB)
  __shared__ float x2s[64][13];       // edge SH (3.3 KB)
  __shared__ float tmparea[8][1280];  // per-wave tmp regions (40.96 KB); prologue: h1T+h2b
  __shared__ int   esrc[64], edst[64];

  const int tid  = threadIdx.x;
  const int lane = tid & 63, w = tid >> 6;
  const int g = w & 3, half = w >> 2;
  const int lr = lane >> 4, lc = lane & 15;
  const int e0 = blockIdx.x * 64;

  float*  h1T = &tmparea[0][0];                          // 64x64 f32 (16 KB)
  __bf16* h2b = (__bf16*)((char*)&tmparea[0][0] + 16384); // 64x64 bf16 (8 KB)

  // ---- phase A: indices, h1 = silu(rad@w1+b1) -> h1T[c*64+e], x2 stage, msg zero
  if (tid < 64)       esrc[tid]      = eidx[e0 + tid];
  else if (tid < 128) edst[tid - 64] = eidx[E + e0 + tid - 64];
  for (int idx = tid; idx < 64 * 64; idx += NT) {
    const int c = idx >> 6, e = idx & 63;
    const float4* r4 = (const float4*)(rad + (size_t)(e0 + e) * 8);
    const float4 ra = r4[0], rb = r4[1];
    float a = b1[c];
    a += ra.x * w1[0*64+c] + ra.y * w1[1*64+c] + ra.z * w1[2*64+c] + ra.w * w1[3*64+c];
    a += rb.x * w1[4*64+c] + rb.y * w1[5*64+c] + rb.z * w1[6*64+c] + rb.w * w1[7*64+c];
    h1T[c * 64 + e] = silu_f(a);
  }
  for (int idx = tid; idx < 64 * 9; idx += NT) {
    const int e = idx / 9, j = idx - e * 9;
    x2s[e][j] = sh[(size_t)(e0 + e) * 9 + j];
  }
  for (int idx = tid; idx < 64 * 121; idx += NT) (&msg[0][0])[idx] = 0.0f;
  __syncthreads();

  // ---- phase B: h2 = silu(h1@w2+b2) -> h2b[e][k] (bf16, k-contiguous)
  for (int idx = tid; idx < 64 * 16; idx += NT) {
    const int c = idx >> 4, eq = (idx & 15) * 4;
    float a0 = b2[c], a1 = b2[c], a2 = b2[c], a3 = b2[c];
    #pragma unroll 8
    for (int i = 0; i < 64; ++i) {
      const float wv = w2[i * 64 + c];
      const float4 h4 = *(const float4*)(&h1T[i * 64 + eq]);
      a0 += h4.x * wv; a1 += h4.y * wv; a2 += h4.z * wv; a3 += h4.w * wv;
    }
    h2b[(eq+0)*64 + c] = (__bf16)silu_f(a0);
    h2b[(eq+1)*64 + c] = (__bf16)silu_f(a1);
    h2b[(eq+2)*64 + c] = (__bf16)silu_f(a2);
    h2b[(eq+3)*64 + c] = (__bf16)silu_f(a3);
  }
  __syncthreads();

  // ---- per-wave B-fragments: lane holds h2[e = g*16+lc][k = kb*32 + lr*8 + j]
  const bf16x8 hB0 = *(const bf16x8*)(h2b + (g*16 + lc)*64 +      lr*8);
  const bf16x8 hB1 = *(const bf16x8*)(h2b + (g*16 + lc)*64 + 32 + lr*8);
  __syncthreads();   // all waves have read h2b; tmparea is now free

  float* tmpw = tmparea[w];

  // ---- paths, split into two 1728-col halves across wave pairs
  if (half == 0) {
    wave_path<0>(cg, w3b, b3, nf, esrc, x2s, tmpw, msg, hB0, hB1, g, lane);
    wave_path<1>(cg, w3b, b3, nf, esrc, x2s, tmpw, msg, hB0, hB1, g, lane);
    wave_path<5>(cg, w3b, b3, nf, esrc, x2s, tmpw, msg, hB0, hB1, g, lane);
    wave_path<7>(cg, w3b, b3, nf, esrc, x2s, tmpw, msg, hB0, hB1, g, lane);
  } else {
    wave_path<2>(cg, w3b, b3, nf, esrc, x2s, tmpw, msg, hB0, hB1, g, lane);
    wave_path<3>(cg, w3b, b3, nf, esrc, x2s, tmpw, msg, hB0, hB1, g, lane);
    wave_path<4>(cg, w3b, b3, nf, esrc, x2s, tmpw, msg, hB0, hB1, g, lane);
    wave_path<6>(cg, w3b, b3, nf, esrc, x2s, tmpw, msg, hB0, hB1, g, lane);
    wave_path<8>(cg, w3b, b3, nf, esrc, x2s, tmpw, msg, hB0, hB1, g, lane);
    wave_path<9>(cg, w3b, b3, nf, esrc, x2s, tmpw, msg, hB0, hB1, g, lane);
    wave_path<10>(cg, w3b, b3, nf, esrc, x2s, tmpw, msg, hB0, hB1, g, lane);
  }
  __syncthreads();   // all msg flushes complete

  // ---- scatter: agg[dst] += msg
  for (int idx = tid; idx < 64 * 120; idx += NT) {
    const int e = idx / 120, d = idx - e * 120;
    atomicAdd(&agg[(size_t)edst[e] * 120 + d], msg[e][d]);
  }
}

// ======================= self-interaction + residual =======================
__global__ __launch_bounds__(128)
void si_kernel(const float* __restrict__ agg, const float* __restrict__ nf,
               const float* __restrict__ w0, const float* __restrict__ wl1,
               const float* __restrict__ wl2, float* __restrict__ out)
{
  __shared__ float a[120];
  const int n = blockIdx.x, tid = threadIdx.x;
  if (tid < 120) a[tid] = agg[(size_t)n * 120 + tid];
  __syncthreads();
  if (tid >= 120) return;
  float s = 0.0f;
  if (tid < 32) {
    const int v = tid;
    #pragma unroll
    for (int u = 0; u < 32; ++u) s += a[u] * w0[u * 32 + v];
    s *= 0.17677669529663687f;    // 1/sqrt(32)
  } else if (tid < 80) {
    const int r = tid - 32, v = r / 3, k = r - 3 * v;
    #pragma unroll
    for (int u = 0; u < 16; ++u) s += a[32 + u * 3 + k] * wl1[u * 16 + v];
    s *= 0.25f;                   // 1/sqrt(16)
  } else {
    const int r = tid - 80, v = r / 5, k = r - 5 * v;
    #pragma unroll
    for (int u = 0; u < 8; ++u) s += a[80 + u * 5 + k] * wl2[u * 8 + v];
    s *= 0.35355339059327373f;    // 1/sqrt(8)
  }
  out[(size_t)n * 120 + tid] = s + nf[(size_t)n * 120 + tid];
}

// ======================= launch =======================
extern "C" void kernel_launch(void* const* d_in, const int* in_sizes, int n_in,
                              void* d_out, int out_size, void* d_ws, size_t ws_size,
                              hipStream_t stream) {
  const float* nf  = (const float*)d_in[0];
  const int*   ei  = (const int*)  d_in[1];
  const float* sh  = (const float*)d_in[2];
  const float* rad = (const float*)d_in[3];
  const float* w1  = (const float*)d_in[4];
  const float* b1  = (const float*)d_in[5];
  const float* w2  = (const float*)d_in[6];
  const float* b2  = (const float*)d_in[7];
  const float* w3  = (const float*)d_in[8];
  const float* b3  = (const float*)d_in[9];
  const float* si0 = (const float*)d_in[10];
  const float* si1 = (const float*)d_in[11];
  const float* si2 = (const float*)d_in[12];
  float* out = (float*)d_out;

  const int N = in_sizes[0] / 120;
  const int E = in_sizes[2] / 9;
  const int W3N = in_sizes[8];          // 64*3456

  float*  agg = (float*)d_ws;
  __bf16* w3b = (__bf16*)((char*)d_ws + (size_t)N * 120 * sizeof(float));
  hipMemsetAsync(agg, 0, (size_t)N * 120 * sizeof(float), stream);

  CgPack cg;
  build_cg(&cg);

  conv_w3<<<(W3N + 255) / 256, 256, 0, stream>>>(w3, w3b, W3N);
  tp_fused<<<E / 64, NT, 0, stream>>>(nf, ei, sh, rad, w1, b1, w2, b2, w3b, b3, agg, E, cg);
  si_kernel<<<N, 128, 0, stream>>>(agg, nf, si0, si1, si2, out);
}